// Round 1
// baseline (604.468 us; speedup 1.0000x reference)
//
#include <hip/hip_runtime.h>
#include <hip/hip_bf16.h>
#include <math.h>

// Problem dims (fixed by reference):
#define B_ 64
#define L_ 512
#define D_ 768
#define H_ 384
#define T_ 9
#define M_ (B_ * L_)   // 32768 rows

__device__ __forceinline__ float gelu_exact(float x) {
    // exact gelu: 0.5 x (1 + erf(x/sqrt(2)))
    return 0.5f * x * (1.0f + erff(x * 0.70710678118654752440f));
}

__device__ __forceinline__ float wredf(float v) {
#pragma unroll
    for (int m = 32; m >= 1; m >>= 1) v += __shfl_xor(v, m, 64);
    return v;
}

// -----------------------------------------------------------------------------
// Kernel 1: emissions = gelu(X @ W1 + b1) @ W2 + b2   (fused; h never hits HBM)
// Block: 64 rows, 256 threads (16x16), 4x4 fp32 microtile over 64-wide hidden
// chunks; per-thread private em accumulator [4 rows][9 tags], shuffle-reduced
// across the 16 threads sharing rows at the end.
// -----------------------------------------------------------------------------
__global__ __launch_bounds__(256) void emissions_kernel(
    const float* __restrict__ X,   // [M_][D_]
    const float* __restrict__ W1,  // [D_][H_]
    const float* __restrict__ b1,  // [H_]
    const float* __restrict__ W2,  // [H_][T_]
    const float* __restrict__ b2,  // [T_]
    float* __restrict__ em)        // [M_][T_]
{
    __shared__ float Xs[16][68];     // transposed X tile: Xs[k][row], pad 68 (16B-aligned float4)
    __shared__ float Ws[16][68];     // W1 tile: Ws[k][col]
    __shared__ float W2s[H_ * T_];   // full W2, 13.8 KB

    const int tid  = threadIdx.x;
    const int tx   = tid & 15;       // col group (hidden)
    const int ty   = tid >> 4;       // row group
    const int row0 = blockIdx.x * 64;

    for (int i = tid; i < H_ * T_; i += 256) W2s[i] = W2[i];

    float emacc[4][9];
#pragma unroll
    for (int r = 0; r < 4; ++r)
#pragma unroll
        for (int t = 0; t < 9; ++t) emacc[r][t] = 0.f;

    for (int jc = 0; jc < H_ / 64; ++jc) {          // 6 hidden chunks of 64
        float acc[4][4];
#pragma unroll
        for (int c = 0; c < 4; ++c) {
            float bv = b1[jc * 64 + (tx << 2) + c];
#pragma unroll
            for (int r = 0; r < 4; ++r) acc[r][c] = bv;
        }

        for (int kc = 0; kc < D_; kc += 16) {
            __syncthreads();  // previous tile fully consumed
            {   // X tile: 64 rows x 16 k, one float4 per thread, store transposed
                int r  = tid >> 2;
                int kk = (tid & 3) << 2;
                float4 xv = *(const float4*)(X + (size_t)(row0 + r) * D_ + kc + kk);
                Xs[kk + 0][r] = xv.x; Xs[kk + 1][r] = xv.y;
                Xs[kk + 2][r] = xv.z; Xs[kk + 3][r] = xv.w;
            }
            {   // W1 tile: 16 k x 64 cols, one float4 per thread
                int k = tid >> 4;
                int c = (tid & 15) << 2;
                *(float4*)&Ws[k][c] =
                    *(const float4*)(W1 + (size_t)(kc + k) * H_ + jc * 64 + c);
            }
            __syncthreads();

#pragma unroll
            for (int kk = 0; kk < 16; ++kk) {
                float4 xv = *(const float4*)&Xs[kk][ty << 2];
                float4 wv = *(const float4*)&Ws[kk][tx << 2];
                float xr[4] = {xv.x, xv.y, xv.z, xv.w};
                float wr[4] = {wv.x, wv.y, wv.z, wv.w};
#pragma unroll
                for (int r = 0; r < 4; ++r)
#pragma unroll
                    for (int c = 0; c < 4; ++c)
                        acc[r][c] = fmaf(xr[r], wr[c], acc[r][c]);
            }
        }

        // epilogue: gelu + rank-64 update into em accumulator
#pragma unroll
        for (int c = 0; c < 4; ++c) {
            int j = jc * 64 + (tx << 2) + c;
            float g[4];
#pragma unroll
            for (int r = 0; r < 4; ++r) g[r] = gelu_exact(acc[r][c]);
#pragma unroll
            for (int t = 0; t < 9; ++t) {
                float w = W2s[j * 9 + t];
#pragma unroll
                for (int r = 0; r < 4; ++r) emacc[r][t] = fmaf(g[r], w, emacc[r][t]);
            }
        }
    }

    // reduce emacc across the 16 threads (tx) sharing the same rows
#pragma unroll
    for (int t = 0; t < 9; ++t)
#pragma unroll
        for (int r = 0; r < 4; ++r) {
            float v = emacc[r][t];
            v += __shfl_xor(v, 1, 64);
            v += __shfl_xor(v, 2, 64);
            v += __shfl_xor(v, 4, 64);
            v += __shfl_xor(v, 8, 64);
            emacc[r][t] = v;
        }

    if (tx == 0) {
#pragma unroll
        for (int r = 0; r < 4; ++r) {
            int row = row0 + (ty << 2) + r;
#pragma unroll
            for (int t = 0; t < 9; ++t)
                em[(size_t)row * 9 + t] = emacc[r][t] + b2[t];
        }
    }
}

// -----------------------------------------------------------------------------
// Kernel 2: CRF numerator + forward (denominator) per batch. One wave per batch;
// lanes 0..8 carry the 9 alpha states, alpha broadcast via __shfl each step.
// Mask storage layout (bool-1B vs int32-4B) detected from first 4 bytes.
// -----------------------------------------------------------------------------
__global__ __launch_bounds__(64) void crf_kernel(
    const float* __restrict__ em,            // [B_][L_][T_]
    const int* __restrict__ labels,          // [B_][L_]
    const unsigned char* __restrict__ mask_bytes,
    const float* __restrict__ start_trans,   // [T_]
    const float* __restrict__ end_trans,     // [T_]
    const float* __restrict__ trans,         // [T_][T_]
    float* __restrict__ out_batch)           // [B_]
{
    const int b    = blockIdx.x;
    const int lane = threadIdx.x;

    __shared__ float es[L_ * T_];      // 18.4 KB
    __shared__ float tr_s[96];
    __shared__ unsigned char ms[L_];

    // bool(1B) vs int32(4B) layout: all-ones bool -> 01 01 01 01; int32 -> 01 00 00 00
    const int mstride =
        (mask_bytes[0] != 0 && mask_bytes[1] == 0 &&
         mask_bytes[2] == 0 && mask_bytes[3] == 0) ? 4 : 1;

    const float* eb = em + (size_t)b * L_ * T_;
    for (int i = lane; i < L_ * T_; i += 64) es[i] = eb[i];
    for (int i = lane; i < T_ * T_; i += 64) tr_s[i] = trans[i];
    for (int i = lane; i < L_; i += 64)
        ms[i] = mask_bytes[((size_t)b * L_ + i) * (size_t)mstride];
    __syncthreads();

    const int* lb = labels + b * L_;

    // ---- numerator (parallel over t) ----
    float emit_s = 0.f, tr_sc = 0.f, mcnt = 0.f;
    for (int t = lane; t < L_; t += 64) {
        if (ms[t]) {
            mcnt += 1.f;
            int tag = lb[t];
            emit_s += es[t * 9 + tag];
            if (t >= 1) tr_sc += tr_s[lb[t - 1] * 9 + tag];
        }
    }
    emit_s = wredf(emit_s);
    tr_sc  = wredf(tr_sc);
    mcnt   = wredf(mcnt);
    int last_idx = (int)mcnt - 1;
    float numer = start_trans[lb[0]] + emit_s + tr_sc + end_trans[lb[last_idx]];

    // ---- forward recursion ----
    const int jj = lane < 9 ? lane : 8;
    float trc[9];
#pragma unroll
    for (int i = 0; i < 9; ++i) trc[i] = tr_s[i * 9 + jj];

    float alpha = (lane < 9) ? (start_trans[jj] + es[jj]) : -1e30f;

    for (int t = 1; t < L_; ++t) {
        float a[9];
#pragma unroll
        for (int i = 0; i < 9; ++i) a[i] = __shfl(alpha, i, 64) + trc[i];
        float mx = a[0];
#pragma unroll
        for (int i = 1; i < 9; ++i) mx = fmaxf(mx, a[i]);
        float s = 0.f;
#pragma unroll
        for (int i = 0; i < 9; ++i) s += __expf(a[i] - mx);
        float nxt = es[t * 9 + jj] + mx + __logf(s);
        if (ms[t] && lane < 9) alpha = nxt;
    }

    // denominator: logsumexp(alpha + end_trans)
    float v = (lane < 9) ? (alpha + end_trans[jj]) : -1e30f;
    float mx = v;
#pragma unroll
    for (int m = 32; m >= 1; m >>= 1) mx = fmaxf(mx, __shfl_xor(mx, m, 64));
    float s = __expf(v - mx);
    s = wredf(s);
    float denom = mx + __logf(s);

    if (lane == 0) out_batch[b] = numer - denom;
}

// -----------------------------------------------------------------------------
// Kernel 3: out = -mean(numer - denom)
// -----------------------------------------------------------------------------
__global__ __launch_bounds__(64) void finalize_kernel(
    const float* __restrict__ bv, float* __restrict__ out)
{
    float v = bv[threadIdx.x];
    v = wredf(v);
    if (threadIdx.x == 0) out[0] = -v * (1.0f / (float)B_);
}

extern "C" void kernel_launch(void* const* d_in, const int* in_sizes, int n_in,
                              void* d_out, int out_size, void* d_ws, size_t ws_size,
                              hipStream_t stream) {
    const float*         enc    = (const float*)d_in[0];
    const int*           labels = (const int*)d_in[1];
    const unsigned char* mask   = (const unsigned char*)d_in[2];
    const float*         W1     = (const float*)d_in[3];
    const float*         b1     = (const float*)d_in[4];
    const float*         W2     = (const float*)d_in[5];
    const float*         b2     = (const float*)d_in[6];
    const float*         st     = (const float*)d_in[7];
    const float*         et     = (const float*)d_in[8];
    const float*         tr     = (const float*)d_in[9];

    float* em    = (float*)d_ws;                 // [M_][T_]  = 1.18 MB
    float* bvals = em + (size_t)M_ * T_;         // [B_]

    emissions_kernel<<<M_ / 64, 256, 0, stream>>>(enc, W1, b1, W2, b2, em);
    crf_kernel<<<B_, 64, 0, stream>>>(em, labels, mask, st, et, tr, bvals);
    finalize_kernel<<<1, 64, 0, stream>>>(bvals, (float*)d_out);
}

// Round 2
// 282.807 us; speedup vs baseline: 2.1374x; 2.1374x over previous
//
#include <hip/hip_runtime.h>
#include <hip/hip_bf16.h>
#include <math.h>

#define B_ 64
#define L_ 512
#define D_ 768
#define H_ 384
#define T_ 9
#define M_ (B_ * L_)   // 32768 rows

typedef __attribute__((ext_vector_type(8))) short short8;
typedef __attribute__((ext_vector_type(4))) float f32x4;

__device__ __forceinline__ float gelu_exact(float x) {
    return 0.5f * x * (1.0f + erff(x * 0.70710678118654752440f));
}

__device__ __forceinline__ unsigned short f2bf(float f) {
    unsigned u = __float_as_uint(f);
    u += 0x7FFFu + ((u >> 16) & 1u);   // RNE
    return (unsigned short)(u >> 16);
}

__device__ __forceinline__ float wredf(float v) {
#pragma unroll
    for (int m = 32; m >= 1; m >>= 1) v += __shfl_xor(v, m, 64);
    return v;
}

// -----------------------------------------------------------------------------
// Kernel 0: W1 [768][384] fp32  ->  W1T [384][768] bf16 (coalesced reads)
// -----------------------------------------------------------------------------
__global__ __launch_bounds__(256) void w1t_kernel(
    const float* __restrict__ W1, unsigned short* __restrict__ W1T)
{
    int idx = blockIdx.x * 256 + threadIdx.x;        // 0 .. 294911
    int k = idx / H_;
    int n = idx - k * H_;
    W1T[n * D_ + k] = f2bf(W1[idx]);
}

// -----------------------------------------------------------------------------
// Kernel 1: emissions = gelu(X @ W1 + b1) @ W2 + b2, bf16 MFMA 16x16x32.
// BM=128, BN=384 (full hidden: X staged exactly once), BK=32, 512 thr, 256 blk.
// Wave (wr,wc): rows 32*wr..+32 (2 m-tiles), cols 192*wc..+192 (12 n-tiles).
// -----------------------------------------------------------------------------
__global__ __launch_bounds__(512, 2) void emis_mfma_kernel(
    const float* __restrict__ X,            // [M_][768] fp32
    const unsigned short* __restrict__ W1T, // [384][768] bf16
    const float* __restrict__ b1,           // [384]
    const float* __restrict__ W2,           // [384][9]
    const float* __restrict__ b2,           // [9]
    float* __restrict__ em)                 // [M_][9]
{
    __shared__ unsigned short As[128 * 40];   // rows padded 32->40 bf16 (80 B)
    __shared__ unsigned short Bs[384 * 40];   // Bs[n][k], padded
    __shared__ float w2s[H_ * T_];            // 13824 B
    __shared__ float b1s[H_];
    __shared__ float b2s[T_];
    __shared__ float em_s[128 * T_];          // 4608 B

    const int t    = threadIdx.x;
    const int lane = t & 63;
    const int w    = t >> 6;          // 0..7
    const int wr   = w >> 1;          // 0..3
    const int wc   = w & 1;           // 0..1
    const int m0   = wr * 32;
    const int n0   = wc * 192;
    const int lm   = lane & 15;
    const int q    = lane >> 4;
    const int lk   = q << 3;          // frag k0: 0,8,16,24
    const int row0 = blockIdx.x * 128;

    for (int i = t; i < H_ * T_; i += 512) w2s[i] = W2[i];
    if (t < H_) b1s[t] = b1[t];
    if (t < T_) b2s[t] = b2[t];

    f32x4 acc0[12], acc1[12];
#pragma unroll
    for (int nt = 0; nt < 12; ++nt) {
        acc0[nt] = (f32x4)0.f;
        acc1[nt] = (f32x4)0.f;
    }

    // staging addressing (constant across K iters)
    const int ar = t >> 2;                 // A row 0..127
    const int ac = (t & 3) << 3;           // A k-offset 0,8,16,24
    const float* xp = X + (size_t)(row0 + ar) * D_ + ac;

    for (int kc = 0; kc < D_; kc += 32) {
        __syncthreads();
        {   // A: 128x32 fp32 -> bf16, 8 elems/thread
            float4 x0 = *(const float4*)(xp + kc);
            float4 x1 = *(const float4*)(xp + kc + 4);
            short8 v;
            v[0] = (short)f2bf(x0.x); v[1] = (short)f2bf(x0.y);
            v[2] = (short)f2bf(x0.z); v[3] = (short)f2bf(x0.w);
            v[4] = (short)f2bf(x1.x); v[5] = (short)f2bf(x1.y);
            v[6] = (short)f2bf(x1.z); v[7] = (short)f2bf(x1.w);
            *(short8*)&As[ar * 40 + ac] = v;
        }
        {   // B: 384 rows x 32 k bf16, 16B chunks; 3 chunks/thread
#pragma unroll
            for (int c = 0; c < 3; ++c) {
                int ch = t + 512 * c;          // 0..1535
                int n  = ch >> 2;
                int ko = (ch & 3) << 3;
                short8 v = *(const short8*)(W1T + (size_t)n * D_ + kc + ko);
                *(short8*)&Bs[n * 40 + ko] = v;
            }
        }
        __syncthreads();

        short8 a0 = *(const short8*)&As[(m0 + lm) * 40 + lk];
        short8 a1 = *(const short8*)&As[(m0 + 16 + lm) * 40 + lk];
#pragma unroll
        for (int nt = 0; nt < 12; ++nt) {
            short8 bf = *(const short8*)&Bs[(n0 + nt * 16 + lm) * 40 + lk];
            acc0[nt] = __builtin_amdgcn_mfma_f32_16x16x32_bf16(a0, bf, acc0[nt], 0, 0, 0);
            acc1[nt] = __builtin_amdgcn_mfma_f32_16x16x32_bf16(a1, bf, acc1[nt], 0, 0, 0);
        }
    }

    // ---- epilogue: +b1, gelu (in place), x W2 -> em partials ----
#pragma unroll
    for (int nt = 0; nt < 12; ++nt) {
        float b1v = b1s[n0 + nt * 16 + lm];
#pragma unroll
        for (int i = 0; i < 4; ++i) {
            acc0[nt][i] = gelu_exact(acc0[nt][i] + b1v);
            acc1[nt][i] = gelu_exact(acc1[nt][i] + b1v);
        }
    }

    float emacc[2][4][T_];
#pragma unroll
    for (int mt = 0; mt < 2; ++mt)
#pragma unroll
        for (int i = 0; i < 4; ++i)
#pragma unroll
            for (int tt = 0; tt < T_; ++tt) emacc[mt][i][tt] = 0.f;

#pragma unroll
    for (int nt = 0; nt < 12; ++nt) {
        int cc = n0 + nt * 16 + lm;
        float w2c[T_];
#pragma unroll
        for (int tt = 0; tt < T_; ++tt) w2c[tt] = w2s[cc * T_ + tt];
#pragma unroll
        for (int i = 0; i < 4; ++i)
#pragma unroll
            for (int tt = 0; tt < T_; ++tt) {
                emacc[0][i][tt] = fmaf(acc0[nt][i], w2c[tt], emacc[0][i][tt]);
                emacc[1][i][tt] = fmaf(acc1[nt][i], w2c[tt], emacc[1][i][tt]);
            }
    }

    // reduce across the 16 cols (lm) sharing each row
#pragma unroll
    for (int mt = 0; mt < 2; ++mt)
#pragma unroll
        for (int i = 0; i < 4; ++i)
#pragma unroll
            for (int tt = 0; tt < T_; ++tt) {
                float v = emacc[mt][i][tt];
                v += __shfl_xor(v, 1, 64);
                v += __shfl_xor(v, 2, 64);
                v += __shfl_xor(v, 4, 64);
                v += __shfl_xor(v, 8, 64);
                emacc[mt][i][tt] = v;
            }

    if (wc == 0 && lm == 0) {
#pragma unroll
        for (int mt = 0; mt < 2; ++mt)
#pragma unroll
            for (int i = 0; i < 4; ++i) {
                int r = wr * 32 + mt * 16 + q * 4 + i;
#pragma unroll
                for (int tt = 0; tt < T_; ++tt)
                    em_s[r * T_ + tt] = emacc[mt][i][tt];
            }
    }
    __syncthreads();
    if (wc == 1 && lm == 0) {
#pragma unroll
        for (int mt = 0; mt < 2; ++mt)
#pragma unroll
            for (int i = 0; i < 4; ++i) {
                int r = wr * 32 + mt * 16 + q * 4 + i;
#pragma unroll
                for (int tt = 0; tt < T_; ++tt)
                    em_s[r * T_ + tt] += emacc[mt][i][tt];
            }
    }
    __syncthreads();

    for (int i = t; i < 128 * T_; i += 512) {
        int r = i / T_, tt = i - r * T_;
        em[(size_t)(row0 + r) * T_ + i - r * T_] = em_s[i] + b2s[tt];
    }
}

// -----------------------------------------------------------------------------
// Kernel 2: CRF via chunked log-semiring scan. One block per batch, 576 thr.
// Phase A: lane (c,i) computes row i of chunk c's 9x9 transfer matrix (8 steps,
// fully lane-local, trans in registers). Phase B: wave 0 combines 64 matrices
// sequentially; wave 1 computes the numerator concurrently.
// -----------------------------------------------------------------------------
__global__ __launch_bounds__(576) void crf_kernel(
    const float* __restrict__ em,            // [B_][512][9]
    const int* __restrict__ labels,
    const unsigned char* __restrict__ maskb,
    const float* __restrict__ st,
    const float* __restrict__ et,
    const float* __restrict__ tr,
    float* __restrict__ outb)
{
    const int b = blockIdx.x;
    const int t = threadIdx.x;

    __shared__ float es[64 * 73];     // chunk-major: es[c*73 + tl*9 + j]
    __shared__ float Ms[64 * 81];     // Ms[c*81 + i*9 + j]
    __shared__ float trs[81];
    __shared__ float red[2];
    __shared__ unsigned char msh[L_];
    __shared__ int lbs[L_];

    const int mstride =
        (maskb[0] != 0 && maskb[1] == 0 && maskb[2] == 0 && maskb[3] == 0) ? 4 : 1;

    const float* eb = em + (size_t)b * L_ * T_;
    for (int i = t; i < L_ * T_; i += 576) {
        int tt = i / T_, j = i - tt * T_;
        es[(tt >> 3) * 73 + (tt & 7) * 9 + j] = eb[i];
    }
    if (t < 81) trs[t] = tr[t];
    for (int i = t; i < L_; i += 576) {
        msh[i] = maskb[((size_t)b * L_ + i) * (size_t)mstride];
        lbs[i] = labels[b * L_ + i];
    }
    __syncthreads();

    // ---- Phase A ----
    {
        const int c  = t / 9;
        const int i0 = t - c * 9;
        float trr[81];
#pragma unroll
        for (int i = 0; i < 81; ++i) trr[i] = trs[i];
        float V[9];
#pragma unroll
        for (int j = 0; j < 9; ++j) V[j] = (j == i0) ? 0.f : -1e30f;

        const int sbeg = (c == 0) ? 1 : 0;
        for (int s = sbeg; s < 8; ++s) {
            int tt = c * 8 + s;
            if (msh[tt]) {
                const float* ep = &es[c * 73 + s * 9];
                float nv[9];
#pragma unroll
                for (int j = 0; j < 9; ++j) {
                    float a[9];
#pragma unroll
                    for (int k = 0; k < 9; ++k) a[k] = V[k] + trr[k * 9 + j];
                    float mx = a[0];
#pragma unroll
                    for (int k = 1; k < 9; ++k) mx = fmaxf(mx, a[k]);
                    float sum = 0.f;
#pragma unroll
                    for (int k = 0; k < 9; ++k) sum += __expf(a[k] - mx);
                    nv[j] = ep[j] + mx + __logf(sum);
                }
#pragma unroll
                for (int j = 0; j < 9; ++j) V[j] = nv[j];
            }
        }
#pragma unroll
        for (int j = 0; j < 9; ++j) Ms[c * 81 + i0 * 9 + j] = V[j];
    }
    __syncthreads();

    const int lane = t & 63;
    const int w    = t >> 6;
    if (w == 0) {
        // ---- Phase B: sequential combine of 64 chunk matrices ----
        const int jj = lane < 9 ? lane : 8;
        float alpha = (lane < 9) ? st[jj] + es[jj] : -1e30f;   // es[c=0,t=0,j]
        for (int c = 0; c < 64; ++c) {
            float a[9];
#pragma unroll
            for (int i = 0; i < 9; ++i) {
                float av = __shfl(alpha, i, 64);
                a[i] = av + Ms[c * 81 + i * 9 + jj];
            }
            float mx = a[0];
#pragma unroll
            for (int i = 1; i < 9; ++i) mx = fmaxf(mx, a[i]);
            float sum = 0.f;
#pragma unroll
            for (int i = 0; i < 9; ++i) sum += __expf(a[i] - mx);
            float nv = mx + __logf(sum);
            if (lane < 9) alpha = nv;
        }
        float v = (lane < 9) ? alpha + et[jj] : -1e30f;
        float mx = v;
#pragma unroll
        for (int m = 32; m >= 1; m >>= 1) mx = fmaxf(mx, __shfl_xor(mx, m, 64));
        float s = __expf(v - mx);
        s = wredf(s);
        if (lane == 0) red[0] = mx + __logf(s);   // denom
    } else if (w == 1) {
        // ---- numerator ----
        float emit_s = 0.f, tr_sc = 0.f, mcnt = 0.f;
        for (int tt = lane; tt < L_; tt += 64) {
            if (msh[tt]) {
                mcnt += 1.f;
                int tag = lbs[tt];
                emit_s += es[(tt >> 3) * 73 + (tt & 7) * 9 + tag];
                if (tt >= 1) tr_sc += trs[lbs[tt - 1] * 9 + tag];
            }
        }
        emit_s = wredf(emit_s);
        tr_sc  = wredf(tr_sc);
        mcnt   = wredf(mcnt);
        if (lane == 0) {
            int last = (int)mcnt - 1;
            red[1] = st[lbs[0]] + emit_s + tr_sc + et[lbs[last]];
        }
    }
    __syncthreads();
    if (t == 0) outb[b] = red[1] - red[0];
}

// -----------------------------------------------------------------------------
// Kernel 3: out = -mean(numer - denom)
// -----------------------------------------------------------------------------
__global__ __launch_bounds__(64) void finalize_kernel(
    const float* __restrict__ bv, float* __restrict__ out)
{
    float v = bv[threadIdx.x];
    v = wredf(v);
    if (threadIdx.x == 0) out[0] = -v * (1.0f / (float)B_);
}

extern "C" void kernel_launch(void* const* d_in, const int* in_sizes, int n_in,
                              void* d_out, int out_size, void* d_ws, size_t ws_size,
                              hipStream_t stream) {
    const float*         enc    = (const float*)d_in[0];
    const int*           labels = (const int*)d_in[1];
    const unsigned char* mask   = (const unsigned char*)d_in[2];
    const float*         W1     = (const float*)d_in[3];
    const float*         b1     = (const float*)d_in[4];
    const float*         W2     = (const float*)d_in[5];
    const float*         b2     = (const float*)d_in[6];
    const float*         st     = (const float*)d_in[7];
    const float*         et     = (const float*)d_in[8];
    const float*         tr     = (const float*)d_in[9];

    float* em             = (float*)d_ws;                         // 1,179,648 B
    float* bvals          = em + (size_t)M_ * T_;                 // 256 B
    unsigned short* W1T   = (unsigned short*)(bvals + B_);        // 589,824 B

    w1t_kernel<<<(D_ * H_) / 256, 256, 0, stream>>>(W1, W1T);
    emis_mfma_kernel<<<M_ / 128, 512, 0, stream>>>(enc, W1T, b1, W2, b2, em);
    crf_kernel<<<B_, 576, 0, stream>>>(em, labels, mask, st, et, tr, bvals);
    finalize_kernel<<<1, 64, 0, stream>>>(bvals, (float*)d_out);
}

// Round 3
// 237.314 us; speedup vs baseline: 2.5471x; 1.1917x over previous
//
#include <hip/hip_runtime.h>
#include <hip/hip_bf16.h>
#include <math.h>

#define B_ 64
#define L_ 512
#define D_ 768
#define H_ 384
#define T_ 9
#define M_ (B_ * L_)   // 32768 rows

typedef __attribute__((ext_vector_type(8))) short short8;
typedef __attribute__((ext_vector_type(4))) float f32x4;

__device__ __forceinline__ float gelu_exact(float x) {
    return 0.5f * x * (1.0f + erff(x * 0.70710678118654752440f));
}

__device__ __forceinline__ unsigned short f2bf(float f) {
    unsigned u = __float_as_uint(f);
    u += 0x7FFFu + ((u >> 16) & 1u);   // RNE
    return (unsigned short)(u >> 16);
}

__device__ __forceinline__ float wredf(float v) {
#pragma unroll
    for (int m = 32; m >= 1; m >>= 1) v += __shfl_xor(v, m, 64);
    return v;
}

// -----------------------------------------------------------------------------
// Kernel 0: build fragment-ordered bf16 weights.
//   W1F[((nt*24 + kc)*64 + lane)*8 + j] = W1[kc*32 + q*8 + j][nt*16 + lm]
//   W2F[(kk*64 + lane)*8 + j]           = (lm<9) ? W2[kk*32 + q*8 + j][lm] : 0
// A wave's b-fragment load becomes a single coalesced 16 B/lane read.
// -----------------------------------------------------------------------------
__global__ __launch_bounds__(256) void prep_kernel(
    const float* __restrict__ W1, const float* __restrict__ W2,
    unsigned short* __restrict__ W1F, unsigned short* __restrict__ W2F)
{
    const int g    = blockIdx.x * 4 + (threadIdx.x >> 6);
    const int lane = threadIdx.x & 63;
    const int lm   = lane & 15;
    const int q    = lane >> 4;
    if (g < 576) {                       // W1F: g = nt*24 + kc
        const int nt = g / 24;
        const int kc = g - nt * 24;
        const int n  = nt * 16 + lm;
        short8 v;
#pragma unroll
        for (int j = 0; j < 8; ++j)
            v[j] = (short)f2bf(W1[(size_t)(kc * 32 + q * 8 + j) * H_ + n]);
        *(short8*)(W1F + ((size_t)g * 64 + lane) * 8) = v;
    } else if (g < 588) {                // W2F: kk = g - 576
        const int kk = g - 576;
        short8 v;
#pragma unroll
        for (int j = 0; j < 8; ++j) {
            int k = kk * 32 + q * 8 + j;
            v[j] = (lm < 9) ? (short)f2bf(W2[(size_t)k * T_ + lm]) : (short)0;
        }
        *(short8*)(W2F + ((size_t)kk * 64 + lane) * 8) = v;
    }
}

// -----------------------------------------------------------------------------
// Kernel 1: emissions = gelu(X @ W1 + b1) @ W2 + b2.
// BM=64, 256 thr (4 waves), grid 512 (2 blocks/CU). Wave = 64 rows x 96 cols
// (4 m-tiles x 6 n-tiles, 24 MFMA/iter). A double-buffered in LDS; B direct
// from global in fragment order (L2-resident); X/B prefetched in registers
// across the barrier. Epilogue: gelu -> Hs (LDS, overlays A bufs) -> second
// MFMA GEMM vs W2F -> em. No giant register epilogue, no spills.
// -----------------------------------------------------------------------------
__global__ __launch_bounds__(256, 2) void emis_mfma_kernel(
    const float* __restrict__ X,             // [M_][768] fp32
    const unsigned short* __restrict__ W1F,  // fragment-ordered bf16
    const float* __restrict__ b1,            // [384]
    const unsigned short* __restrict__ W2F,  // fragment-ordered bf16
    const float* __restrict__ b2,            // [9]
    float* __restrict__ em)                  // [M_][9]
{
    __shared__ unsigned short Hs[64 * 392];  // 50176 B; first 5120 shorts double as As[2]
    unsigned short* As = Hs;                 // As[buf] at buf*2560, row stride 40

    const int t    = threadIdx.x;
    const int lane = t & 63;
    const int w    = t >> 6;        // wave index = n-group 0..3 (96 cols each)
    const int lm   = lane & 15;
    const int q    = lane >> 4;
    const int row0 = blockIdx.x * 64;

    const int ar  = t >> 2;         // staging row 0..63
    const int ako = (t & 3) << 3;   // staging k-offset 0,8,16,24
    const float* xp = X + (size_t)(row0 + ar) * D_ + ako;

    f32x4 acc[4][6];
#pragma unroll
    for (int mt = 0; mt < 4; ++mt)
#pragma unroll
        for (int i = 0; i < 6; ++i) acc[mt][i] = (f32x4)0.f;

    // ---- prologue: tile 0 ----
    float4 x0 = *(const float4*)(xp);
    float4 x1 = *(const float4*)(xp + 4);
    short8 bcur[6];
#pragma unroll
    for (int i = 0; i < 6; ++i)
        bcur[i] = *(const short8*)(W1F + (((size_t)(w * 6 + i) * 24) * 64 + lane) * 8);
    {
        short8 v;
        v[0] = (short)f2bf(x0.x); v[1] = (short)f2bf(x0.y);
        v[2] = (short)f2bf(x0.z); v[3] = (short)f2bf(x0.w);
        v[4] = (short)f2bf(x1.x); v[5] = (short)f2bf(x1.y);
        v[6] = (short)f2bf(x1.z); v[7] = (short)f2bf(x1.w);
        *(short8*)&As[ar * 40 + ako] = v;
    }

    int buf = 0;
    for (int kc = 0; kc < 24; ++kc) {
        const bool notlast = (kc < 23);
        float4 xn0, xn1;
        short8 bnxt[6];
        if (notlast) {   // register prefetch: NOT drained by the barrier
            xn0 = *(const float4*)(xp + (kc + 1) * 32);
            xn1 = *(const float4*)(xp + (kc + 1) * 32 + 4);
#pragma unroll
            for (int i = 0; i < 6; ++i)
                bnxt[i] = *(const short8*)(W1F +
                    (((size_t)(w * 6 + i) * 24 + kc + 1) * 64 + lane) * 8);
        }
        __syncthreads();               // As[buf] ready
        short8 af[4];
#pragma unroll
        for (int mt = 0; mt < 4; ++mt)
            af[mt] = *(const short8*)&As[buf * 2560 + (mt * 16 + lm) * 40 + (q << 3)];
#pragma unroll
        for (int mt = 0; mt < 4; ++mt)
#pragma unroll
            for (int i = 0; i < 6; ++i)
                acc[mt][i] = __builtin_amdgcn_mfma_f32_16x16x32_bf16(
                    af[mt], bcur[i], acc[mt][i], 0, 0, 0);
        if (notlast) {
            short8 v;
            v[0] = (short)f2bf(xn0.x); v[1] = (short)f2bf(xn0.y);
            v[2] = (short)f2bf(xn0.z); v[3] = (short)f2bf(xn0.w);
            v[4] = (short)f2bf(xn1.x); v[5] = (short)f2bf(xn1.y);
            v[6] = (short)f2bf(xn1.z); v[7] = (short)f2bf(xn1.w);
            *(short8*)&As[(buf ^ 1) * 2560 + ar * 40 + ako] = v;
#pragma unroll
            for (int i = 0; i < 6; ++i) bcur[i] = bnxt[i];
            buf ^= 1;
        }
    }
    __syncthreads();   // all A reads complete; safe to reuse Hs region

    // ---- epilogue A: +b1, gelu, h -> Hs (bf16, row stride 392) ----
#pragma unroll
    for (int i = 0; i < 6; ++i) {
        const int col = w * 96 + i * 16 + lm;
        const float b1v = b1[col];
#pragma unroll
        for (int mt = 0; mt < 4; ++mt)
#pragma unroll
            for (int r = 0; r < 4; ++r) {
                float h = gelu_exact(acc[mt][i][r] + b1v);
                Hs[(mt * 16 + q * 4 + r) * 392 + col] = f2bf(h);
            }
    }
    __syncthreads();

    // ---- epilogue B: em = h @ W2 via MFMA; wave w handles m-tile w ----
    f32x4 e = (f32x4)0.f;
#pragma unroll
    for (int kk = 0; kk < 12; ++kk) {
        short8 ah = *(const short8*)&Hs[(w * 16 + lm) * 392 + kk * 32 + (q << 3)];
        short8 bw = *(const short8*)(W2F + ((size_t)(kk * 64 + lane)) * 8);
        e = __builtin_amdgcn_mfma_f32_16x16x32_bf16(ah, bw, e, 0, 0, 0);
    }
    if (lm < 9) {
        const float b2v = b2[lm];
#pragma unroll
        for (int r = 0; r < 4; ++r)
            em[(size_t)(row0 + w * 16 + q * 4 + r) * T_ + lm] = e[r] + b2v;
    }
}

// -----------------------------------------------------------------------------
// Kernel 2: CRF chunked log-semiring scan. 64 blocks x 576 threads.
// Phase A: lane (c,i) computes row i of chunk c's 9x9 transfer matrix; trans
// read via wave-uniform LDS broadcast (NO 81-register copy -> no spills).
// Phase B: wave 0 combines 64 matrices; wave 1 computes the numerator.
// -----------------------------------------------------------------------------
__global__ __launch_bounds__(576) void crf_kernel(
    const float* __restrict__ em,
    const int* __restrict__ labels,
    const unsigned char* __restrict__ maskb,
    const float* __restrict__ st,
    const float* __restrict__ et,
    const float* __restrict__ tr,
    float* __restrict__ outb)
{
    const int b = blockIdx.x;
    const int t = threadIdx.x;

    __shared__ float es[64 * 73];
    __shared__ float Ms[64 * 81];
    __shared__ float trs[81];     // [from][to]
    __shared__ float trsT[81];    // [to][from]
    __shared__ float red[2];
    __shared__ unsigned char msh[L_];
    __shared__ int lbs[L_];

    const int mstride =
        (maskb[0] != 0 && maskb[1] == 0 && maskb[2] == 0 && maskb[3] == 0) ? 4 : 1;

    const float* eb = em + (size_t)b * L_ * T_;
    for (int i = t; i < L_ * T_; i += 576) {
        int tt = i / T_, j = i - tt * T_;
        es[(tt >> 3) * 73 + (tt & 7) * 9 + j] = eb[i];
    }
    if (t < 81) {
        float v = tr[t];
        trs[t] = v;
        int k = t / 9, j = t - k * 9;
        trsT[j * 9 + k] = v;
    }
    for (int i = t; i < L_; i += 576) {
        msh[i] = maskb[((size_t)b * L_ + i) * (size_t)mstride];
        lbs[i] = labels[b * L_ + i];
    }
    __syncthreads();

    // ---- Phase A: per-chunk transfer matrices ----
    {
        const int c  = t / 9;
        const int i0 = t - c * 9;
        float V[9];
#pragma unroll
        for (int j = 0; j < 9; ++j) V[j] = (j == i0) ? 0.f : -1e30f;

        const int sbeg = (c == 0) ? 1 : 0;
        for (int s = sbeg; s < 8; ++s) {
            int tt = c * 8 + s;
            if (msh[tt]) {
                const float* ep = &es[c * 73 + s * 9];
                float nv[9];
#pragma unroll
                for (int j = 0; j < 9; ++j) {
                    const float* trc = &trsT[j * 9];   // wave-uniform LDS broadcast
                    float a[9];
#pragma unroll
                    for (int k = 0; k < 9; ++k) a[k] = V[k] + trc[k];
                    float mx = a[0];
#pragma unroll
                    for (int k = 1; k < 9; ++k) mx = fmaxf(mx, a[k]);
                    float sum = 0.f;
#pragma unroll
                    for (int k = 0; k < 9; ++k) sum += __expf(a[k] - mx);
                    nv[j] = ep[j] + mx + __logf(sum);
                }
#pragma unroll
                for (int j = 0; j < 9; ++j) V[j] = nv[j];
            }
        }
#pragma unroll
        for (int j = 0; j < 9; ++j) Ms[c * 81 + i0 * 9 + j] = V[j];
    }
    __syncthreads();

    const int lane = t & 63;
    const int w    = t >> 6;
    if (w == 0) {
        // ---- Phase B: combine 64 chunk matrices ----
        const int jj = lane < 9 ? lane : 8;
        float alpha = (lane < 9) ? st[jj] + es[jj] : -1e30f;
        for (int c = 0; c < 64; ++c) {
            float a[9];
#pragma unroll
            for (int i = 0; i < 9; ++i) {
                float av = __shfl(alpha, i, 64);
                a[i] = av + Ms[c * 81 + i * 9 + jj];
            }
            float mx = a[0];
#pragma unroll
            for (int i = 1; i < 9; ++i) mx = fmaxf(mx, a[i]);
            float sum = 0.f;
#pragma unroll
            for (int i = 0; i < 9; ++i) sum += __expf(a[i] - mx);
            float nv = mx + __logf(sum);
            if (lane < 9) alpha = nv;
        }
        float v = (lane < 9) ? alpha + et[jj] : -1e30f;
        float mx = v;
#pragma unroll
        for (int m = 32; m >= 1; m >>= 1) mx = fmaxf(mx, __shfl_xor(mx, m, 64));
        float s = __expf(v - mx);
        s = wredf(s);
        if (lane == 0) red[0] = mx + __logf(s);
    } else if (w == 1) {
        // ---- numerator ----
        float emit_s = 0.f, tr_sc = 0.f, mcnt = 0.f;
        for (int tt = lane; tt < L_; tt += 64) {
            if (msh[tt]) {
                mcnt += 1.f;
                int tag = lbs[tt];
                emit_s += es[(tt >> 3) * 73 + (tt & 7) * 9 + tag];
                if (tt >= 1) tr_sc += trs[lbs[tt - 1] * 9 + tag];
            }
        }
        emit_s = wredf(emit_s);
        tr_sc  = wredf(tr_sc);
        mcnt   = wredf(mcnt);
        if (lane == 0) {
            int last = (int)mcnt - 1;
            red[1] = st[lbs[0]] + emit_s + tr_sc + et[lbs[last]];
        }
    }
    __syncthreads();
    if (t == 0) outb[b] = red[1] - red[0];
}

// -----------------------------------------------------------------------------
// Kernel 3: out = -mean
// -----------------------------------------------------------------------------
__global__ __launch_bounds__(64) void finalize_kernel(
    const float* __restrict__ bv, float* __restrict__ out)
{
    float v = bv[threadIdx.x];
    v = wredf(v);
    if (threadIdx.x == 0) out[0] = -v * (1.0f / (float)B_);
}

extern "C" void kernel_launch(void* const* d_in, const int* in_sizes, int n_in,
                              void* d_out, int out_size, void* d_ws, size_t ws_size,
                              hipStream_t stream) {
    const float*         enc    = (const float*)d_in[0];
    const int*           labels = (const int*)d_in[1];
    const unsigned char* mask   = (const unsigned char*)d_in[2];
    const float*         W1     = (const float*)d_in[3];
    const float*         b1     = (const float*)d_in[4];
    const float*         W2     = (const float*)d_in[5];
    const float*         b2     = (const float*)d_in[6];
    const float*         st     = (const float*)d_in[7];
    const float*         et     = (const float*)d_in[8];
    const float*         tr     = (const float*)d_in[9];

    float* em           = (float*)d_ws;                    // 1,179,648 B
    float* bvals        = em + (size_t)M_ * T_;            // 256 B
    unsigned short* W1F = (unsigned short*)(bvals + B_);   // 589,824 B
    unsigned short* W2F = W1F + (size_t)576 * 64 * 8;      // 12,288 B

    prep_kernel<<<147, 256, 0, stream>>>(W1, W2, W1F, W2F);
    emis_mfma_kernel<<<M_ / 64, 256, 0, stream>>>(enc, W1F, b1, W2F, b2, em);
    crf_kernel<<<B_, 576, 0, stream>>>(em, labels, mask, st, et, tr, bvals);
    finalize_kernel<<<1, 64, 0, stream>>>(bvals, (float*)d_out);
}